// Round 2
// baseline (296.242 us; speedup 1.0000x reference)
//
#include <hip/hip_runtime.h>
#include <hip/hip_fp16.h>

typedef float f4 __attribute__((ext_vector_type(4)));
typedef short s8 __attribute__((ext_vector_type(8)));
typedef unsigned short u16x4 __attribute__((ext_vector_type(4)));
typedef unsigned short u16x8 __attribute__((ext_vector_type(8)));

// ---- ws layout (bytes) ----
// embB   : 1 MiB    .. 5 MiB   (4096*512 bf16)
// rbT    : 5 MiB    .. 37 MiB  (64*512*512 bf16, [n][o][i])
// gemmT  : 37 MiB   .. 53 MiB  (2 slices of 4096*512 f32, [b][o])

__device__ __forceinline__ unsigned short f2bf(float f) {
    unsigned int u = __float_as_uint(f);
    unsigned int r = (u + 0x7fffu + ((u >> 16) & 1u)) >> 16;
    return (unsigned short)r;
}

// blocks [0,2048): emb f32->bf16. blocks [2048, 2048+4096): rbT transpose, 64x64 tiles.
__global__ __launch_bounds__(256) void prep_kernel(const float* __restrict__ emb,
                                                   unsigned short* __restrict__ embB,
                                                   const float* __restrict__ rb,
                                                   unsigned short* __restrict__ rbT) {
    int bid = blockIdx.x;
    int t = threadIdx.x;
    if (bid < 2048) {
        int g = (bid * 256 + t) * 4;
        f4 v = *(const f4*)(emb + g);
        u16x4 o;
        o[0] = f2bf(v[0]); o[1] = f2bf(v[1]); o[2] = f2bf(v[2]); o[3] = f2bf(v[3]);
        *(u16x4*)(embB + g) = o;
        return;
    }
    __shared__ float tl[64][65];
    int b2 = bid - 2048;
    int n = b2 >> 6;
    int rem = b2 & 63;
    int i0 = (rem & 7) * 64, o0 = (rem >> 3) * 64;
    int oq = t & 15, ir = t >> 4;
#pragma unroll
    for (int k = 0; k < 4; k++) {
        int r = ir + 16 * k;
        f4 v = *(const f4*)(rb + (size_t)(n * 512 + i0 + r) * 512 + o0 + oq * 4);
        tl[r][oq * 4 + 0] = v[0]; tl[r][oq * 4 + 1] = v[1];
        tl[r][oq * 4 + 2] = v[2]; tl[r][oq * 4 + 3] = v[3];
    }
    __syncthreads();
    int ic = t & 7, or0 = t >> 3;
#pragma unroll
    for (int k = 0; k < 2; k++) {
        int orow = or0 + 32 * k;
        u16x8 w;
#pragma unroll
        for (int j = 0; j < 8; j++) w[j] = f2bf(tl[ic * 8 + j][orow]);
        *(u16x8*)(rbT + (size_t)(n * 512 + o0 + orow) * 512 + i0 + ic * 8) = w;
    }
}

// Main fused GEMM, v3: K-chunks of 128 (16 MFMA per att-scale: fmac VALU halved vs v2),
// register pipeline (distance-1 A-frag prefetch) + distance-2 LDS staging with counted
// waits. __launch_bounds__(256,3): VGPR cap 170 so embF[4][4] (64 VGPR) stays resident
// (r0's (256,4)=128 cap forced rematerialization -> 16 hidden loads/iter).
// LDS: 2x16KB dbuf + 4KB att = 36.8 KB; occupancy 3 blocks/CU (VGPR-limited, intended).
// Epilogue: fold bias, then LDS-transpose the 64x64 tile -> gemmT in [b][o] layout
// so ln_kernel is fully coalesced.
__global__ __launch_bounds__(256, 3) void gemm_fold(const unsigned short* __restrict__ embB,
                                                    const unsigned short* __restrict__ rbT,
                                                    const int* __restrict__ ids,
                                                    const float* __restrict__ rel_att,
                                                    const float* __restrict__ relb,
                                                    float* __restrict__ gemmT) {
    __shared__ unsigned short bS[2][64 * 128];   // [buf][o_local*128 + i], 16B-slot xor-swizzle
    __shared__ unsigned int attH[32][32];        // [n][h] = half2(att[m0+h], att[m0+h+32])

    const int t = threadIdx.x;
    const int wv = t >> 6;
    const int ln = t & 63;
    const int q  = ln >> 4;     // quad 0..3
    const int lm = ln & 15;
    const int g  = blockIdx.x;
    const int o0 = (g & 7) * 64;                  // fastest -> XCD-aligned o slice
    const int m0 = ((g >> 3) & 63) * 64;
    const int nz = g >> 9;                        // n-half 0/1
    const int nbase = nz * 32;

    // stage lane constants: chunk = 4 rows x 256B; row-in-chunk rr, 16B slot lc
    const int rr = ln >> 4;                       // 0..3
    const int lc = ln & 15;                       // 0..15
    int loffj[4];
#pragma unroll
    for (int j = 0; j < 4; j++)
        loffj[j] = (j * 4 + rr) * 512 + ((lc ^ (j * 4 + rr)) * 8);
    // A-frag read offsets (bytes): row wv*16+lm, slot (ks*4+q)^lm
    int aoff[4];
#pragma unroll
    for (int ks = 0; ks < 4; ks++)
        aoff[ks] = (wv * 16 + lm) * 256 + (((ks * 4 + q) ^ lm) * 16);

    // async stage of one 64o x 128i bf16 tile (16KB); wave's 4 chunks cover its own
    // rows [wv*16, wv*16+16) -> wave-private producer/consumer, no barrier in K-loop.
    auto stage = [&](int sx, int buf) {
        const int icc = sx >> 5;
        const int n   = nbase + (sx & 31);
        const unsigned short* gb = rbT + (size_t)n * 262144 + (size_t)(o0 + wv * 16) * 512 + icc * 128;
#pragma unroll
        for (int j = 0; j < 4; j++) {
            const unsigned short* gp = gb + loffj[j];
            void* l = (char*)(&bS[buf][0]) + (wv * 4 + j) * 1024;
            __builtin_amdgcn_global_load_lds((const __attribute__((address_space(1))) void*)gp,
                                             (__attribute__((address_space(3))) void*)l,
                                             16, 0, 0);
        }
    };

    stage(0, 0);
    stage(1, 1);

    // att tile gathered via ids, packed to f16 pairs (m, m+32)
#pragma unroll
    for (int k = 0; k < 4; k++) {
        int e = t + 256 * k;                      // 0..1023
        int n = e >> 5, h = e & 31;
        float a0 = rel_att[(size_t)ids[m0 + h] * 64 + nbase + n];
        float a1 = rel_att[(size_t)ids[m0 + h + 32] * 64 + nbase + n];
        __half2 hp = __floats2half2_rn(a0, a1);
        attH[n][h] = *(unsigned int*)&hp;
    }
    __syncthreads();

    const f4 z = {0.f, 0.f, 0.f, 0.f};
    f4 acc[4] = {z, z, z, z};
    s8 embF[4][4];                                // 64 VGPR, resident across the n loop

    asm volatile("s_waitcnt vmcnt(4)" ::: "memory");   // tile 0 landed (tile 1 in flight)
    s8 cA[4], cB[4];
    {
        const char* bp0 = (const char*)&bS[0][0];
#pragma unroll
        for (int ks = 0; ks < 4; ks++) cA[ks] = *(const s8*)(bp0 + aoff[ks]);
    }
    unsigned int aA0 = attH[0][lm], aA1 = attH[0][lm + 16];
    unsigned int aB0, aB1;

    // iterate s: consume tile s (regs cF/ca*), stage tile s+2 into buf s&1 (WAR resolved
    // by lgkmcnt(2)), prefetch tile s+1 frags+att into nF/na*. vmcnt(4): tile s+1
    // resident, s+2 stays in flight (~2 iterations of latency cover).
    auto iterate = [&](int s, int bufc, s8 (&cF)[4], unsigned int ca0, unsigned int ca1,
                       s8 (&nF)[4], unsigned int& na0, unsigned int& na1) {
        asm volatile("s_waitcnt lgkmcnt(2)" ::: "memory");  // cur A-frags in regs
        const int nl = s & 31;
        if (nl == 0) {
            const int icc = s >> 5;
            const unsigned short* eb = embB + (size_t)(m0 + lm) * 512 + icc * 128 + q * 8;
#pragma unroll
            for (int ks = 0; ks < 4; ks++)
#pragma unroll
                for (int ms = 0; ms < 4; ms++)
                    embF[ks][ms] = *(const s8*)(eb + ms * 8192 + ks * 32);
        }
        if (s < 126) {
            stage(s + 2, bufc);
            asm volatile("s_waitcnt vmcnt(4)" ::: "memory");  // tile s+1 resident
        } else {
            asm volatile("s_waitcnt vmcnt(0)" ::: "memory");
        }
        if (s < 127) {
            const char* bn = (const char*)&bS[bufc ^ 1][0];
#pragma unroll
            for (int ks = 0; ks < 4; ks++) nF[ks] = *(const s8*)(bn + aoff[ks]);
            const int nn = (nl + 1) & 31;
            na0 = attH[nn][lm];
            na1 = attH[nn][lm + 16];
        }
        __builtin_amdgcn_s_setprio(1);
        f4 an[4];
#pragma unroll
        for (int ms = 0; ms < 4; ms++)
            an[ms] = __builtin_amdgcn_mfma_f32_16x16x32_bf16(cF[0], embF[0][ms], z, 0, 0, 0);
#pragma unroll
        for (int ks = 1; ks < 4; ks++)
#pragma unroll
            for (int ms = 0; ms < 4; ms++)
                an[ms] = __builtin_amdgcn_mfma_f32_16x16x32_bf16(cF[ks], embF[ks][ms], an[ms], 0, 0, 0);
        __builtin_amdgcn_s_setprio(0);
        float2 f0 = __half22float2(*(const __half2*)&ca0);
        float2 f1 = __half22float2(*(const __half2*)&ca1);
        acc[0] += f0.x * an[0];
        acc[1] += f1.x * an[1];
        acc[2] += f0.y * an[2];
        acc[3] += f1.y * an[3];
    };

    for (int s = 0; s < 128; s += 2) {
        iterate(s,     0, cA, aA0, aA1, cB, aB0, aB1);
        iterate(s + 1, 1, cB, aB0, aB1, cA, aA0, aA1);
    }

    // bias fold: acc[ms] += sum_{n in half} att(n, m) * relb[nbase+n][o]
    const float* rbb = relb + (size_t)nbase * 512 + o0 + wv * 16 + q * 4;
#pragma unroll 4
    for (int n = 0; n < 32; n++) {
        unsigned int p0 = attH[n][lm], p1 = attH[n][lm + 16];
        float2 f0 = __half22float2(*(const __half2*)&p0);
        float2 f1 = __half22float2(*(const __half2*)&p1);
        f4 rb4 = *(const f4*)(rbb + (size_t)n * 512);
        acc[0] += f0.x * rb4;
        acc[1] += f1.x * rb4;
        acc[2] += f0.y * rb4;
        acc[3] += f1.y * rb4;
    }

    // transpose epilogue: acc (o-major fragments) -> [b][o] tile via LDS, then
    // coalesced 64B-per-row stores. bS is dead; reuse as float[64][68].
    __syncthreads();
    float* T = (float*)&bS[0][0];
#pragma unroll
    for (int ms = 0; ms < 4; ms++)
#pragma unroll
        for (int r = 0; r < 4; r++)
            T[(ms * 16 + lm) * 68 + wv * 16 + q * 4 + r] = acc[ms][r];
    __syncthreads();
    float* gB = gemmT + (size_t)nz * 4096 * 512;
    const int mrow = t >> 2;
    const int oc = (t & 3) * 16;
    const float* Tr = T + mrow * 68 + oc;
    float* gp = gB + (size_t)(m0 + mrow) * 512 + o0 + oc;
#pragma unroll
    for (int j = 0; j < 4; j++)
        *(f4*)(gp + j * 4) = *(const f4*)(Tr + j * 4);
}

// LayerNorm over o (512) per b, [b][o] layout: pure-register, no LDS, no barrier.
// 16 threads per row; 16 b per block; grid 256.
__global__ __launch_bounds__(256) void ln_kernel(const float* __restrict__ g0,
                                                 const float* __restrict__ g1,
                                                 float* __restrict__ out) {
    int t = threadIdx.x;
    int b = blockIdx.x * 16 + (t >> 4);
    int l = t & 15;
    const float* p0 = g0 + (size_t)b * 512 + l * 4;
    const float* p1 = g1 + (size_t)b * 512 + l * 4;
    f4 v[8];
    float s1 = 0.f, s2 = 0.f;
#pragma unroll
    for (int j = 0; j < 8; j++) {
        f4 a = *(const f4*)(p0 + j * 64);
        f4 c = *(const f4*)(p1 + j * 64);
        f4 w = a + c;
        v[j] = w;
        s1 += w[0] + w[1] + w[2] + w[3];
        s2 += w[0] * w[0] + w[1] * w[1] + w[2] * w[2] + w[3] * w[3];
    }
#pragma unroll
    for (int off = 8; off; off >>= 1) {
        s1 += __shfl_xor(s1, off, 64);
        s2 += __shfl_xor(s2, off, 64);
    }
    float mu = s1 * (1.f / 512.f);
    float var = s2 * (1.f / 512.f) - mu * mu;
    float rs = rsqrtf(var + 1e-5f);
    float* po = out + (size_t)b * 512 + l * 4;
#pragma unroll
    for (int j = 0; j < 8; j++) {
        f4 w = (v[j] - mu) * rs;
        *(f4*)(po + j * 64) = w;
    }
}

extern "C" void kernel_launch(void* const* d_in, const int* in_sizes, int n_in,
                              void* d_out, int out_size, void* d_ws, size_t ws_size,
                              hipStream_t stream) {
    (void)in_sizes; (void)n_in; (void)out_size; (void)ws_size;
    const float* emb      = (const float*)d_in[0];
    const int*   proj_ids = (const int*)d_in[1];
    const float* rel_att  = (const float*)d_in[2];
    const float* rel_base = (const float*)d_in[3];
    const float* rel_bias = (const float*)d_in[4];
    float* out = (float*)d_out;

    char* w = (char*)d_ws;
    unsigned short* embB  = (unsigned short*)(w + (1u << 20));
    unsigned short* rbT   = (unsigned short*)(w + 5u * (1u << 20));
    float*          gemmT = (float*)(w + 37u * (1u << 20));   // 2 slices of 8 MiB, [b][o]
    float*          g1    = gemmT + (size_t)4096 * 512;

    prep_kernel<<<dim3(2048 + 4096), dim3(256), 0, stream>>>(emb, embB, rel_base, rbT);
    gemm_fold<<<dim3(1024), dim3(256), 0, stream>>>(embB, rbT, proj_ids, rel_att, rel_bias, gemmT);
    ln_kernel<<<dim3(256), dim3(256), 0, stream>>>(gemmT, g1, out);
}

// Round 4
// 284.569 us; speedup vs baseline: 1.0410x; 1.0410x over previous
//
#include <hip/hip_runtime.h>

typedef float f4 __attribute__((ext_vector_type(4)));
typedef short s8 __attribute__((ext_vector_type(8)));
typedef unsigned short u16x4 __attribute__((ext_vector_type(4)));
typedef unsigned short u16x8 __attribute__((ext_vector_type(8)));

// ---- ws layout (bytes) ----
// embB   : 1 MiB    .. 5 MiB   (4096*512 bf16)
// rbT    : 5 MiB    .. 37 MiB  (64*512*512 bf16, [n][o][i])
// gemmT  : 37 MiB   .. 53 MiB  (2 slices of 4096*512 f32, [b][o])

__device__ __forceinline__ unsigned short f2bf(float f) {
    unsigned int u = __float_as_uint(f);
    unsigned int r = (u + 0x7fffu + ((u >> 16) & 1u)) >> 16;
    return (unsigned short)r;
}

// blocks [0,512): rbT transpose, one block per (n, o-tile), loops 8 i-tiles with
// double-buffered LDS (prev version: 4096 tiny blocks, 64B/thread, latency-bound).
// blocks [512, 2560): emb f32->bf16.
__global__ __launch_bounds__(256) void prep_kernel(const float* __restrict__ emb,
                                                   unsigned short* __restrict__ embB,
                                                   const float* __restrict__ rb,
                                                   unsigned short* __restrict__ rbT) {
    int bid = blockIdx.x;
    int t = threadIdx.x;
    if (bid >= 512) {
        int g = ((bid - 512) * 256 + t) * 4;
        f4 v = *(const f4*)(emb + g);
        u16x4 o;
        o[0] = f2bf(v[0]); o[1] = f2bf(v[1]); o[2] = f2bf(v[2]); o[3] = f2bf(v[3]);
        *(u16x4*)(embB + g) = o;
        return;
    }
    __shared__ float tl[2][64][65];
    int n = bid >> 3;
    int o0 = (bid & 7) * 64;
    int oq = t & 15, ir = t >> 4;          // load-phase index
    int ic = t & 7, or0 = t >> 3;          // write-phase index
    const float* rbn = rb + (size_t)n * 512 * 512;
    unsigned short* rbTn = rbT + (size_t)n * 512 * 512;

    f4 v[4];
#pragma unroll
    for (int k = 0; k < 4; k++)
        v[k] = *(const f4*)(rbn + (size_t)(ir + 16 * k) * 512 + o0 + oq * 4);

    for (int ii = 0; ii < 8; ii++) {
        int buf = ii & 1;
#pragma unroll
        for (int k = 0; k < 4; k++) {
            int r = ir + 16 * k;
            tl[buf][r][oq * 4 + 0] = v[k][0]; tl[buf][r][oq * 4 + 1] = v[k][1];
            tl[buf][r][oq * 4 + 2] = v[k][2]; tl[buf][r][oq * 4 + 3] = v[k][3];
        }
        if (ii < 7) {
            int i0n = (ii + 1) * 64;
#pragma unroll
            for (int k = 0; k < 4; k++)
                v[k] = *(const f4*)(rbn + (size_t)(i0n + ir + 16 * k) * 512 + o0 + oq * 4);
        }
        __syncthreads();
        int i0 = ii * 64;
#pragma unroll
        for (int k = 0; k < 2; k++) {
            int orow = or0 + 32 * k;
            u16x8 w;
#pragma unroll
            for (int j = 0; j < 8; j++) w[j] = f2bf(tl[buf][ic * 8 + j][orow]);
            *(u16x8*)(rbTn + (size_t)(o0 + orow) * 512 + i0 + ic * 8) = w;
        }
        // iter ii+2 overwrites tl[buf]; the barrier inside iter ii+1 orders it
        // after this iter's reads -> safe with one barrier per iteration.
    }
}

// Main fused GEMM — r0 champion body (162 us measured):
// same-iter ds_reads + lgkmcnt(0) + distance-2 in-place staging, f32 attS.
// (v2/v3's explicit register pipeline + counted lgkm pinned the schedule and
//  lost occupancy: 178/199 us. Lesson recorded.)
// Kept from v2/v3 (validated): bias fold into epilogue, LDS-transpose to [b][o].
// Added (only new loop element): s_setprio around the MFMA cluster.
__global__ __launch_bounds__(256, 4) void gemm_fold(const unsigned short* __restrict__ embB,
                                                    const unsigned short* __restrict__ rbT,
                                                    const int* __restrict__ ids,
                                                    const float* __restrict__ rel_att,
                                                    const float* __restrict__ relb,
                                                    float* __restrict__ gemmT) {
    __shared__ unsigned short bS[2][64 * 128];    // [buf][o_local*128 + i_local] (xor-swizzled)
    __shared__ float attS[32][64];                // [n][m] broadcast layout

    const int t = threadIdx.x;
    const int wv = t >> 6;
    const int ln = t & 63;
    const int q  = ln >> 4;     // quad 0..3
    const int lm = ln & 15;
    const int g  = blockIdx.x;
    const int o0 = (g & 7) * 64;                  // fastest -> XCD-aligned o slice
    const int m0 = ((g >> 3) & 63) * 64;
    const int nz = g >> 9;                        // n-half 0/1
    const int nbase = nz * 32;

    // async stage of one 64o x 128i bf16 tile; this wave's 4 chunks cover
    // rows [wv*16, wv*16+16) — wave-private producer/consumer.
    auto stage = [&](int s, int buf) {
        int ic = s >> 5, n = nbase + (s & 31);
#pragma unroll
        for (int j = 0; j < 4; j++) {
            int c   = wv * 4 + j;                 // chunk 0..15
            int r   = c * 4 + q;                  // o_local
            int c16 = (ln & 15) ^ (r & 15);       // logical i-chunk for this lane's slot
            const unsigned short* gp = rbT + (size_t)(n * 512 + o0 + r) * 512 + ic * 128 + c16 * 8;
            void* l = (char*)(&bS[buf][0]) + c * 1024;
            __builtin_amdgcn_global_load_lds((const __attribute__((address_space(1))) void*)gp,
                                             (__attribute__((address_space(3))) void*)l,
                                             16, 0, 0);
        }
    };

    stage(0, 0);
    stage(1, 1);

    // stage att tile [32 n][64 m], gathered via ids: 8 per thread
#pragma unroll
    for (int k = 0; k < 8; k++) {
        int idx = t + 256 * k;
        int n = idx >> 6, m = idx & 63;
        attS[n][m] = rel_att[(size_t)ids[m0 + m] * 64 + nbase + n];
    }
    __syncthreads();                              // the ONLY block barrier before epilogue

    const f4 z = {0.f, 0.f, 0.f, 0.f};
    f4 acc[4] = {z, z, z, z};
    s8 embF[4][4];

    for (int s = 0; s < 128; s++) {
        int nl = s & 31;
        // tile s landed when only tile s+1's 4 loads remain outstanding
        if (s < 127) asm volatile("s_waitcnt vmcnt(4)" ::: "memory");
        else         asm volatile("s_waitcnt vmcnt(0)" ::: "memory");

        if (nl == 0) {
            // emb fragments for this i-chunk: register-resident across the n loop.
            int ic = s >> 5;
#pragma unroll
            for (int ks = 0; ks < 4; ks++)
#pragma unroll
                for (int ms = 0; ms < 4; ms++)
                    embF[ks][ms] = *(const s8*)(embB + (size_t)(m0 + ms * 16 + lm) * 512
                                                + ic * 128 + ks * 32 + q * 8);
        }

        const unsigned short* bp = &bS[s & 1][0];
        // A-fragments for this wave's 16 o-rows: 4 ds_read_b128
        s8 aF[4];
#pragma unroll
        for (int ks = 0; ks < 4; ks++) {
            int c16 = (ks * 4 + q) ^ lm;          // un-swizzle
            aF[ks] = *(const s8*)(bp + (wv * 16 + lm) * 128 + c16 * 8);
        }
        // fragments now in registers -> safe to overwrite this buffer (WAR resolved)
        asm volatile("s_waitcnt lgkmcnt(0)" ::: "memory");
        if (s + 2 < 128) stage(s + 2, s & 1);

        __builtin_amdgcn_s_setprio(1);
        f4 an[4];
#pragma unroll
        for (int ms = 0; ms < 4; ms++)
            an[ms] = __builtin_amdgcn_mfma_f32_16x16x32_bf16(aF[0], embF[0][ms], z, 0, 0, 0);
#pragma unroll
        for (int ks = 1; ks < 4; ks++)
#pragma unroll
            for (int ms = 0; ms < 4; ms++)
                an[ms] = __builtin_amdgcn_mfma_f32_16x16x32_bf16(aF[ks], embF[ks][ms], an[ms], 0, 0, 0);
        __builtin_amdgcn_s_setprio(0);
#pragma unroll
        for (int ms = 0; ms < 4; ms++) {
            float av = attS[nl][ms * 16 + lm];    // 4-way broadcast read
            acc[ms] += av * an[ms];
        }
    }

    // bias fold: acc[ms] += sum_{n in half} att(n, m) * relb[nbase+n][o]
    // (relb f4 is wave-broadcast: o depends only on wv,q,r)
    const float* rbb = relb + (size_t)nbase * 512 + o0 + wv * 16 + q * 4;
#pragma unroll 4
    for (int n = 0; n < 32; n++) {
        f4 rb4 = *(const f4*)(rbb + (size_t)n * 512);
#pragma unroll
        for (int ms = 0; ms < 4; ms++)
            acc[ms] += attS[n][ms * 16 + lm] * rb4;
    }

    // transpose epilogue: acc (o-major fragments) -> [b][o] tile via LDS, then
    // coalesced stores. bS is dead; reuse as float[64][68] (68 keeps 16B alignment).
    __syncthreads();                              // waves drift; protect bS reads
    float* T = (float*)&bS[0][0];
#pragma unroll
    for (int ms = 0; ms < 4; ms++)
#pragma unroll
        for (int r = 0; r < 4; r++)
            T[(ms * 16 + lm) * 68 + wv * 16 + q * 4 + r] = acc[ms][r];
    __syncthreads();
    float* gB = gemmT + (size_t)nz * 4096 * 512;
    const int mrow = t >> 2;
    const int oc = (t & 3) * 16;
    const float* Tr = T + mrow * 68 + oc;
    float* gp = gB + (size_t)(m0 + mrow) * 512 + o0 + oc;
#pragma unroll
    for (int j = 0; j < 4; j++)
        *(f4*)(gp + j * 4) = *(const f4*)(Tr + j * 4);
}

// LayerNorm over o (512) per b, [b][o] layout: pure-register, no LDS, no barrier.
// 16 threads per row; 16 b per block; grid 256.
__global__ __launch_bounds__(256) void ln_kernel(const float* __restrict__ g0,
                                                 const float* __restrict__ g1,
                                                 float* __restrict__ out) {
    int t = threadIdx.x;
    int b = blockIdx.x * 16 + (t >> 4);
    int l = t & 15;
    const float* p0 = g0 + (size_t)b * 512 + l * 4;
    const float* p1 = g1 + (size_t)b * 512 + l * 4;
    f4 v[8];
    float s1 = 0.f, s2 = 0.f;
#pragma unroll
    for (int j = 0; j < 8; j++) {
        f4 a = *(const f4*)(p0 + j * 64);
        f4 c = *(const f4*)(p1 + j * 64);
        f4 w = a + c;
        v[j] = w;
        s1 += w[0] + w[1] + w[2] + w[3];
        s2 += w[0] * w[0] + w[1] * w[1] + w[2] * w[2] + w[3] * w[3];
    }
#pragma unroll
    for (int off = 8; off; off >>= 1) {
        s1 += __shfl_xor(s1, off, 64);
        s2 += __shfl_xor(s2, off, 64);
    }
    float mu = s1 * (1.f / 512.f);
    float var = s2 * (1.f / 512.f) - mu * mu;
    float rs = rsqrtf(var + 1e-5f);
    float* po = out + (size_t)b * 512 + l * 4;
#pragma unroll
    for (int j = 0; j < 8; j++) {
        f4 w = (v[j] - mu) * rs;
        *(f4*)(po + j * 64) = w;
    }
}

extern "C" void kernel_launch(void* const* d_in, const int* in_sizes, int n_in,
                              void* d_out, int out_size, void* d_ws, size_t ws_size,
                              hipStream_t stream) {
    (void)in_sizes; (void)n_in; (void)out_size; (void)ws_size;
    const float* emb      = (const float*)d_in[0];
    const int*   proj_ids = (const int*)d_in[1];
    const float* rel_att  = (const float*)d_in[2];
    const float* rel_base = (const float*)d_in[3];
    const float* rel_bias = (const float*)d_in[4];
    float* out = (float*)d_out;

    char* w = (char*)d_ws;
    unsigned short* embB  = (unsigned short*)(w + (1u << 20));
    unsigned short* rbT   = (unsigned short*)(w + 5u * (1u << 20));
    float*          gemmT = (float*)(w + 37u * (1u << 20));   // 2 slices of 8 MiB, [b][o]
    float*          g1    = gemmT + (size_t)4096 * 512;

    prep_kernel<<<dim3(512 + 2048), dim3(256), 0, stream>>>(emb, embB, rel_base, rbT);
    gemm_fold<<<dim3(1024), dim3(256), 0, stream>>>(embB, rbT, proj_ids, rel_att, rel_bias, gemmT);
    ln_kernel<<<dim3(256), dim3(256), 0, stream>>>(gemmT, g1, out);
}

// Round 5
// 278.746 us; speedup vs baseline: 1.0628x; 1.0209x over previous
//
#include <hip/hip_runtime.h>

typedef float f4 __attribute__((ext_vector_type(4)));
typedef short s8 __attribute__((ext_vector_type(8)));
typedef unsigned short u16x4 __attribute__((ext_vector_type(4)));
typedef unsigned short u16x8 __attribute__((ext_vector_type(8)));

// ---- ws layout (bytes) ----
// embB   : 1 MiB    .. 5 MiB   (4096*512 bf16)
// rbT    : 5 MiB    .. 37 MiB  (64*512*512 bf16, [n][o][i])
// gemmT  : 37 MiB   .. 53 MiB  (2 slices of 4096*512 f32, [b][o])

__device__ __forceinline__ unsigned short f2bf(float f) {
    unsigned int u = __float_as_uint(f);
    unsigned int r = (u + 0x7fffu + ((u >> 16) & 1u)) >> 16;
    return (unsigned short)r;
}

// blocks [0,1024): rbT transpose, one block per (n, o-tile, i-half); 4 i-tiles each,
// double-buffered LDS. 1024 blocks -> 4 blocks/CU (vs 512 -> 2): latency hiding.
// blocks [1024, 3072): emb f32->bf16.
__global__ __launch_bounds__(256) void prep_kernel(const float* __restrict__ emb,
                                                   unsigned short* __restrict__ embB,
                                                   const float* __restrict__ rb,
                                                   unsigned short* __restrict__ rbT) {
    int bid = blockIdx.x;
    int t = threadIdx.x;
    if (bid >= 1024) {
        int g = ((bid - 1024) * 256 + t) * 4;
        f4 v = *(const f4*)(emb + g);
        u16x4 o;
        o[0] = f2bf(v[0]); o[1] = f2bf(v[1]); o[2] = f2bf(v[2]); o[3] = f2bf(v[3]);
        *(u16x4*)(embB + g) = o;
        return;
    }
    __shared__ float tl[2][64][65];
    int n = bid >> 4;
    int sub = bid & 15;
    int o0 = (sub & 7) * 64;
    int ibase = (sub >> 3) * 4;            // i-tile range [ibase, ibase+4)
    int oq = t & 15, ir = t >> 4;          // load-phase index
    int ic = t & 7, or0 = t >> 3;          // write-phase index
    const float* rbn = rb + (size_t)n * 262144;
    unsigned short* rbTn = rbT + (size_t)n * 262144;

    f4 v[4];
#pragma unroll
    for (int k = 0; k < 4; k++)
        v[k] = *(const f4*)(rbn + (size_t)(ibase * 64 + ir + 16 * k) * 512 + o0 + oq * 4);

    for (int jj = 0; jj < 4; jj++) {
        int ii = ibase + jj;
        int buf = jj & 1;
#pragma unroll
        for (int k = 0; k < 4; k++) {
            int r = ir + 16 * k;
            tl[buf][r][oq * 4 + 0] = v[k][0]; tl[buf][r][oq * 4 + 1] = v[k][1];
            tl[buf][r][oq * 4 + 2] = v[k][2]; tl[buf][r][oq * 4 + 3] = v[k][3];
        }
        if (jj < 3) {
            int i0n = (ii + 1) * 64;
#pragma unroll
            for (int k = 0; k < 4; k++)
                v[k] = *(const f4*)(rbn + (size_t)(i0n + ir + 16 * k) * 512 + o0 + oq * 4);
        }
        __syncthreads();
        int i0 = ii * 64;
#pragma unroll
        for (int k = 0; k < 2; k++) {
            int orow = or0 + 32 * k;
            u16x8 w;
#pragma unroll
            for (int j = 0; j < 8; j++) w[j] = f2bf(tl[buf][ic * 8 + j][orow]);
            *(u16x8*)(rbTn + (size_t)(o0 + orow) * 512 + i0 + ic * 8) = w;
        }
        // iter jj+2 overwrites tl[buf]; the barrier inside iter jj+1 orders it
        // after this iter's reads -> safe with one barrier per iteration.
    }
}

// Main fused GEMM — r0 champion body, NO setprio.
// Evidence trail: r0 (no setprio) = 162 us; v2/v3/R4 (all with setprio) = 178/199/199.
// setprio is a side-effecting instr -> compiler can't interleave the VALU tail
// (16 acc-fmacs + attS ds_reads + staging addr math) into the MFMA cluster; the
// tail serializes after the MFMAs (~+20%/iter). m190's GEMM-null confirmed here
// as an outright regression. DO NOT re-add setprio to this lockstep structure.
// Kept (validated): bias fold into epilogue, LDS-transpose to [b][o] store.
__global__ __launch_bounds__(256, 4) void gemm_fold(const unsigned short* __restrict__ embB,
                                                    const unsigned short* __restrict__ rbT,
                                                    const int* __restrict__ ids,
                                                    const float* __restrict__ rel_att,
                                                    const float* __restrict__ relb,
                                                    float* __restrict__ gemmT) {
    __shared__ unsigned short bS[2][64 * 128];    // [buf][o_local*128 + i_local] (xor-swizzled)
    __shared__ float attS[32][64];                // [n][m] broadcast layout

    const int t = threadIdx.x;
    const int wv = t >> 6;
    const int ln = t & 63;
    const int q  = ln >> 4;     // quad 0..3
    const int lm = ln & 15;
    const int g  = blockIdx.x;
    const int o0 = (g & 7) * 64;                  // fastest -> XCD-aligned o slice
    const int m0 = ((g >> 3) & 63) * 64;
    const int nz = g >> 9;                        // n-half 0/1
    const int nbase = nz * 32;

    // async stage of one 64o x 128i bf16 tile; this wave's 4 chunks cover
    // rows [wv*16, wv*16+16) — wave-private producer/consumer.
    auto stage = [&](int s, int buf) {
        int ic = s >> 5, n = nbase + (s & 31);
#pragma unroll
        for (int j = 0; j < 4; j++) {
            int c   = wv * 4 + j;                 // chunk 0..15
            int r   = c * 4 + q;                  // o_local
            int c16 = (ln & 15) ^ (r & 15);       // logical i-chunk for this lane's slot
            const unsigned short* gp = rbT + (size_t)(n * 512 + o0 + r) * 512 + ic * 128 + c16 * 8;
            void* l = (char*)(&bS[buf][0]) + c * 1024;
            __builtin_amdgcn_global_load_lds((const __attribute__((address_space(1))) void*)gp,
                                             (__attribute__((address_space(3))) void*)l,
                                             16, 0, 0);
        }
    };

    stage(0, 0);
    stage(1, 1);

    // stage att tile [32 n][64 m], gathered via ids: 8 per thread
#pragma unroll
    for (int k = 0; k < 8; k++) {
        int idx = t + 256 * k;
        int n = idx >> 6, m = idx & 63;
        attS[n][m] = rel_att[(size_t)ids[m0 + m] * 64 + nbase + n];
    }
    __syncthreads();                              // the ONLY block barrier before epilogue

    const f4 z = {0.f, 0.f, 0.f, 0.f};
    f4 acc[4] = {z, z, z, z};
    s8 embF[4][4];

    for (int s = 0; s < 128; s++) {
        int nl = s & 31;
        // tile s landed when only tile s+1's 4 loads remain outstanding
        if (s < 127) asm volatile("s_waitcnt vmcnt(4)" ::: "memory");
        else         asm volatile("s_waitcnt vmcnt(0)" ::: "memory");

        if (nl == 0) {
            // emb fragments for this i-chunk: register-resident across the n loop.
            int ic = s >> 5;
#pragma unroll
            for (int ks = 0; ks < 4; ks++)
#pragma unroll
                for (int ms = 0; ms < 4; ms++)
                    embF[ks][ms] = *(const s8*)(embB + (size_t)(m0 + ms * 16 + lm) * 512
                                                + ic * 128 + ks * 32 + q * 8);
        }

        const unsigned short* bp = &bS[s & 1][0];
        // A-fragments for this wave's 16 o-rows: 4 ds_read_b128
        s8 aF[4];
#pragma unroll
        for (int ks = 0; ks < 4; ks++) {
            int c16 = (ks * 4 + q) ^ lm;          // un-swizzle
            aF[ks] = *(const s8*)(bp + (wv * 16 + lm) * 128 + c16 * 8);
        }
        // fragments now in registers -> safe to overwrite this buffer (WAR resolved)
        asm volatile("s_waitcnt lgkmcnt(0)" ::: "memory");
        if (s + 2 < 128) stage(s + 2, s & 1);

        f4 an[4];
#pragma unroll
        for (int ms = 0; ms < 4; ms++)
            an[ms] = __builtin_amdgcn_mfma_f32_16x16x32_bf16(aF[0], embF[0][ms], z, 0, 0, 0);
#pragma unroll
        for (int ks = 1; ks < 4; ks++)
#pragma unroll
            for (int ms = 0; ms < 4; ms++)
                an[ms] = __builtin_amdgcn_mfma_f32_16x16x32_bf16(aF[ks], embF[ks][ms], an[ms], 0, 0, 0);
#pragma unroll
        for (int ms = 0; ms < 4; ms++) {
            float av = attS[nl][ms * 16 + lm];    // 4-way broadcast read
            acc[ms] += av * an[ms];
        }
    }

    // bias fold: acc[ms] += sum_{n in half} att(n, m) * relb[nbase+n][o]
    // (relb f4 is wave-broadcast: o depends only on wv,q,r)
    const float* rbb = relb + (size_t)nbase * 512 + o0 + wv * 16 + q * 4;
#pragma unroll 4
    for (int n = 0; n < 32; n++) {
        f4 rb4 = *(const f4*)(rbb + (size_t)n * 512);
#pragma unroll
        for (int ms = 0; ms < 4; ms++)
            acc[ms] += attS[n][ms * 16 + lm] * rb4;
    }

    // transpose epilogue: acc (o-major fragments) -> [b][o] tile via LDS, then
    // coalesced stores. bS is dead; reuse as float[64][68] (68 keeps 16B alignment).
    __syncthreads();                              // waves drift; protect bS reads
    float* T = (float*)&bS[0][0];
#pragma unroll
    for (int ms = 0; ms < 4; ms++)
#pragma unroll
        for (int r = 0; r < 4; r++)
            T[(ms * 16 + lm) * 68 + wv * 16 + q * 4 + r] = acc[ms][r];
    __syncthreads();
    float* gB = gemmT + (size_t)nz * 4096 * 512;
    const int mrow = t >> 2;
    const int oc = (t & 3) * 16;
    const float* Tr = T + mrow * 68 + oc;
    float* gp = gB + (size_t)(m0 + mrow) * 512 + o0 + oc;
#pragma unroll
    for (int j = 0; j < 4; j++)
        *(f4*)(gp + j * 4) = *(const f4*)(Tr + j * 4);
}

// LayerNorm over o (512) per b, [b][o] layout: pure-register, no LDS.
// 4 rows per block (64 lanes/row, wave-wide shuffle reduce); grid 1024
// (prev 256 blocks = 1 block/CU was latency-starved).
__global__ __launch_bounds__(256) void ln_kernel(const float* __restrict__ g0,
                                                 const float* __restrict__ g1,
                                                 float* __restrict__ out) {
    int t = threadIdx.x;
    int b = blockIdx.x * 4 + (t >> 6);
    int l = t & 63;
    const float* p0 = g0 + (size_t)b * 512 + l * 4;
    const float* p1 = g1 + (size_t)b * 512 + l * 4;
    f4 v[2];
    float s1 = 0.f, s2 = 0.f;
#pragma unroll
    for (int j = 0; j < 2; j++) {
        f4 a = *(const f4*)(p0 + j * 256);
        f4 c = *(const f4*)(p1 + j * 256);
        f4 w = a + c;
        v[j] = w;
        s1 += w[0] + w[1] + w[2] + w[3];
        s2 += w[0] * w[0] + w[1] * w[1] + w[2] * w[2] + w[3] * w[3];
    }
#pragma unroll
    for (int off = 32; off; off >>= 1) {
        s1 += __shfl_xor(s1, off, 64);
        s2 += __shfl_xor(s2, off, 64);
    }
    float mu = s1 * (1.f / 512.f);
    float var = s2 * (1.f / 512.f) - mu * mu;
    float rs = rsqrtf(var + 1e-5f);
    float* po = out + (size_t)b * 512 + l * 4;
#pragma unroll
    for (int j = 0; j < 2; j++) {
        f4 w = (v[j] - mu) * rs;
        *(f4*)(po + j * 256) = w;
    }
}

extern "C" void kernel_launch(void* const* d_in, const int* in_sizes, int n_in,
                              void* d_out, int out_size, void* d_ws, size_t ws_size,
                              hipStream_t stream) {
    (void)in_sizes; (void)n_in; (void)out_size; (void)ws_size;
    const float* emb      = (const float*)d_in[0];
    const int*   proj_ids = (const int*)d_in[1];
    const float* rel_att  = (const float*)d_in[2];
    const float* rel_base = (const float*)d_in[3];
    const float* rel_bias = (const float*)d_in[4];
    float* out = (float*)d_out;

    char* w = (char*)d_ws;
    unsigned short* embB  = (unsigned short*)(w + (1u << 20));
    unsigned short* rbT   = (unsigned short*)(w + 5u * (1u << 20));
    float*          gemmT = (float*)(w + 37u * (1u << 20));   // 2 slices of 8 MiB, [b][o]
    float*          g1    = gemmT + (size_t)4096 * 512;

    prep_kernel<<<dim3(1024 + 2048), dim3(256), 0, stream>>>(emb, embB, rel_base, rbT);
    gemm_fold<<<dim3(1024), dim3(256), 0, stream>>>(embB, rbT, proj_ids, rel_att, rel_bias, gemmT);
    ln_kernel<<<dim3(1024), dim3(256), 0, stream>>>(gemmT, g1, out);
}